// Round 4
// baseline (98.932 us; speedup 1.0000x reference)
//
#include <hip/hip_runtime.h>
#include <math.h>

#define EPS 1e-8f
#define MARGIN 0.5f

typedef float f4 __attribute__((ext_vector_type(4)));

// ---------------- Kernel 1: per-batch-row positive cosine + anchor norm ----
__global__ void pos_sim_kernel(const float* __restrict__ anchor,
                               const float* __restrict__ pos,
                               float2* __restrict__ pn,
                               int B) {
    int wave = (blockIdx.x * blockDim.x + threadIdx.x) >> 6;
    int lane = threadIdx.x & 63;
    if (wave >= B) return;

    const f4 a = *(reinterpret_cast<const f4*>(anchor + (size_t)wave * 256) + lane);
    const f4 p = *(reinterpret_cast<const f4*>(pos    + (size_t)wave * 256) + lane);

    float dot = a.x * p.x + a.y * p.y + a.z * p.z + a.w * p.w;
    float na  = a.x * a.x + a.y * a.y + a.z * a.z + a.w * a.w;
    float nb  = p.x * p.x + p.y * p.y + p.z * p.z + p.w * p.w;

    #pragma unroll
    for (int off = 32; off > 0; off >>= 1) {
        dot += __shfl_xor(dot, off);
        na  += __shfl_xor(na,  off);
        nb  += __shfl_xor(nb,  off);
    }
    if (lane == 0) {
        float sna = sqrtf(na);
        float2 r;
        r.x = dot / fmaxf(sna * sqrtf(nb), EPS);  // pos_sim
        r.y = sna;                                 // ||anchor||
        pn[wave] = r;
    }
}

// ---------------- Kernel 2: XCD-sliced negatives ---------------------------
// blockIdx.x%8 -> XCD group k. Group k only processes negatives whose idx is
// in anchor slice [k*B/8,(k+1)*B/8) -> 0.5 MB working set, L2-resident.
// Every group scans all N in 64-contiguous chunks (coalesced idx load +
// ballot); matching slots popped 4 at a time into the pipelined body.
// Correct for ANY block->XCD mapping (slices partition [0,B), each group
// scans every chunk); the %8 mapping is a locality heuristic only.
__global__ void __launch_bounds__(256) neg_kernel(
        const float* __restrict__ anchor,
        const float* __restrict__ neg,
        const int*  __restrict__ idx,
        const float2* __restrict__ pn,
        float* __restrict__ sums,
        float* __restrict__ counts,
        int N, int B) {
    const int lane  = threadIdx.x & 63;
    const int xcd   = blockIdx.x & 7;
    const int xblk  = blockIdx.x >> 3;                       // block ordinal within group
    const int wid   = threadIdx.x >> 6;
    const int wpb   = blockDim.x >> 6;                       // waves per block
    const int xwave = xblk * wpb + wid;                      // wave ordinal within group
    const int gwaves = (gridDim.x >> 3) * wpb;               // waves per group

    const int slice_lo = (int)(((long long)xcd * B) >> 3);
    const int slice_hi = (int)(((long long)(xcd + 1) * B) >> 3);

    const int nchunks = (N + 63) >> 6;

    for (int ch = xwave; ch < nchunks; ch += gwaves) {
        const int base = ch << 6;
        const int myn  = base + lane;
        const int myb  = (myn < N) ? idx[myn] : -1;
        unsigned long long mask = __ballot(myb >= slice_lo && myb < slice_hi);

        // ---- 4-wide pipelined processing of matching slots ----
        while (__popcll(mask) >= 4) {
            int i0 = __ffsll((unsigned long long)mask) - 1; mask &= mask - 1;
            int i1 = __ffsll((unsigned long long)mask) - 1; mask &= mask - 1;
            int i2 = __ffsll((unsigned long long)mask) - 1; mask &= mask - 1;
            int i3 = __ffsll((unsigned long long)mask) - 1; mask &= mask - 1;
            const int b0 = __shfl(myb, i0), b1 = __shfl(myb, i1);
            const int b2 = __shfl(myb, i2), b3 = __shfl(myb, i3);
            const int n0 = base + i0, n1 = base + i1, n2 = base + i2, n3 = base + i3;

            // anchor gathers: slice is L2-resident
            const f4 g0 = *(reinterpret_cast<const f4*>(anchor + (size_t)b0 * 256) + lane);
            const f4 g1 = *(reinterpret_cast<const f4*>(anchor + (size_t)b1 * 256) + lane);
            const f4 g2 = *(reinterpret_cast<const f4*>(anchor + (size_t)b2 * 256) + lane);
            const f4 g3 = *(reinterpret_cast<const f4*>(anchor + (size_t)b3 * 256) + lane);
            // neg stream: non-temporal, read-once
            const f4 v0 = __builtin_nontemporal_load(reinterpret_cast<const f4*>(neg + (size_t)n0 * 256) + lane);
            const f4 v1 = __builtin_nontemporal_load(reinterpret_cast<const f4*>(neg + (size_t)n1 * 256) + lane);
            const f4 v2 = __builtin_nontemporal_load(reinterpret_cast<const f4*>(neg + (size_t)n2 * 256) + lane);
            const f4 v3 = __builtin_nontemporal_load(reinterpret_cast<const f4*>(neg + (size_t)n3 * 256) + lane);

            float d0 = g0.x*v0.x + g0.y*v0.y + g0.z*v0.z + g0.w*v0.w;
            float d1 = g1.x*v1.x + g1.y*v1.y + g1.z*v1.z + g1.w*v1.w;
            float d2 = g2.x*v2.x + g2.y*v2.y + g2.z*v2.z + g2.w*v2.w;
            float d3 = g3.x*v3.x + g3.y*v3.y + g3.z*v3.z + g3.w*v3.w;
            float q0 = v0.x*v0.x + v0.y*v0.y + v0.z*v0.z + v0.w*v0.w;
            float q1 = v1.x*v1.x + v1.y*v1.y + v1.z*v1.z + v1.w*v1.w;
            float q2 = v2.x*v2.x + v2.y*v2.y + v2.z*v2.z + v2.w*v2.w;
            float q3 = v3.x*v3.x + v3.y*v3.y + v3.z*v3.z + v3.w*v3.w;

            #pragma unroll
            for (int off = 32; off > 0; off >>= 1) {
                d0 += __shfl_xor(d0, off);  d1 += __shfl_xor(d1, off);
                d2 += __shfl_xor(d2, off);  d3 += __shfl_xor(d3, off);
                q0 += __shfl_xor(q0, off);  q1 += __shfl_xor(q1, off);
                q2 += __shfl_xor(q2, off);  q3 += __shfl_xor(q3, off);
            }

            if (lane == 0) {
                const float2 p0 = pn[b0], p1 = pn[b1], p2 = pn[b2], p3 = pn[b3];
                float t0 = fmaxf(MARGIN + d0 / fmaxf(p0.y * sqrtf(q0), EPS) - p0.x, 0.0f);
                float t1 = fmaxf(MARGIN + d1 / fmaxf(p1.y * sqrtf(q1), EPS) - p1.x, 0.0f);
                float t2 = fmaxf(MARGIN + d2 / fmaxf(p2.y * sqrtf(q2), EPS) - p2.x, 0.0f);
                float t3 = fmaxf(MARGIN + d3 / fmaxf(p3.y * sqrtf(q3), EPS) - p3.x, 0.0f);
                atomicAdd(&sums[b0], t0);  atomicAdd(&counts[b0], 1.0f);
                atomicAdd(&sums[b1], t1);  atomicAdd(&counts[b1], 1.0f);
                atomicAdd(&sums[b2], t2);  atomicAdd(&counts[b2], 1.0f);
                atomicAdd(&sums[b3], t3);  atomicAdd(&counts[b3], 1.0f);
            }
        }
        // ---- remainder (<4 hits) ----
        while (mask) {
            int i0 = __ffsll((unsigned long long)mask) - 1; mask &= mask - 1;
            const int b = __shfl(myb, i0);
            const int n = base + i0;
            const f4 g = *(reinterpret_cast<const f4*>(anchor + (size_t)b * 256) + lane);
            const f4 v = __builtin_nontemporal_load(reinterpret_cast<const f4*>(neg + (size_t)n * 256) + lane);
            float d = g.x*v.x + g.y*v.y + g.z*v.z + g.w*v.w;
            float q = v.x*v.x + v.y*v.y + v.z*v.z + v.w*v.w;
            #pragma unroll
            for (int off = 32; off > 0; off >>= 1) {
                d += __shfl_xor(d, off);
                q += __shfl_xor(q, off);
            }
            if (lane == 0) {
                const float2 p = pn[b];
                float t = fmaxf(MARGIN + d / fmaxf(p.y * sqrtf(q), EPS) - p.x, 0.0f);
                atomicAdd(&sums[b], t);
                atomicAdd(&counts[b], 1.0f);
            }
        }
    }
}

// ---------------- Kernel 3: segment means -> scalar (parallel) -------------
__global__ void finalize_kernel(const float* __restrict__ sums,
                                const float* __restrict__ counts,
                                float* __restrict__ out, int B) {
    int i = blockIdx.x * blockDim.x + threadIdx.x;
    float local = 0.0f;
    if (i < B) {
        float c = counts[i];
        local = (c > 0.0f) ? (sums[i] / c) : 0.0f;
    }
    #pragma unroll
    for (int off = 32; off > 0; off >>= 1)
        local += __shfl_xor(local, off);
    if ((threadIdx.x & 63) == 0)
        atomicAdd(out, local / (float)B);
}

extern "C" void kernel_launch(void* const* d_in, const int* in_sizes, int n_in,
                              void* d_out, int out_size, void* d_ws, size_t ws_size,
                              hipStream_t stream) {
    const float* anchor = (const float*)d_in[0];
    const float* pos    = (const float*)d_in[1];
    const float* neg    = (const float*)d_in[2];
    const int*   idx    = (const int*)d_in[3];

    const int D = 256;
    int B = in_sizes[0] / D;   // 4096
    int N = in_sizes[3];       // 262144

    float2* pn     = (float2*)d_ws;            // B float2
    float*  sums   = (float*)(pn + B);         // B floats
    float*  counts = sums + B;                 // B floats

    hipMemsetAsync(sums, 0, 2 * (size_t)B * sizeof(float), stream);
    hipMemsetAsync(d_out, 0, sizeof(float), stream);

    // kernel 1: B waves
    {
        int threads = 256;
        int blocks = (B + 3) / 4;
        pos_sim_kernel<<<blocks, threads, 0, stream>>>(anchor, pos, pn, B);
    }

    // kernel 2: 2048 blocks = 8 XCD groups x 256 blocks; 1024 waves/group
    {
        int threads = 256;
        int blocks  = 2048;
        neg_kernel<<<blocks, threads, 0, stream>>>(anchor, neg, idx, pn,
                                                   sums, counts, N, B);
    }

    // kernel 3: parallel reduce to scalar
    {
        int threads = 256;
        int blocks = (B + threads - 1) / threads;  // 16
        finalize_kernel<<<blocks, threads, 0, stream>>>(sums, counts, (float*)d_out, B);
    }
}

// Round 5
// 77.807 us; speedup vs baseline: 1.2715x; 1.2715x over previous
//
#include <hip/hip_runtime.h>
#include <math.h>

#define EPS 1e-8f
#define MARGIN 0.5f
#define NEG_PER_WAVE 32

typedef float f4 __attribute__((ext_vector_type(4)));

__device__ __forceinline__ float dot4(const f4 a, const f4 b) {
    return a.x * b.x + a.y * b.y + a.z * b.z + a.w * b.w;
}

// ---------------- Kernel 1: positive cosine + anchor norm + zero accums ----
// One wave per row, f4 per lane. Also zeroes sums/counts (so no memsets).
__global__ void pos_sim_kernel(const float* __restrict__ anchor,
                               const float* __restrict__ pos,
                               float2* __restrict__ pn,
                               float* __restrict__ sums,
                               float* __restrict__ counts,
                               int B) {
    const int tid  = blockIdx.x * blockDim.x + threadIdx.x;
    const int wave = tid >> 6;
    const int lane = threadIdx.x & 63;

    // fused zeroing of segment accumulators (total threads = 64*B >= 2*B)
    if (tid < B) sums[tid] = 0.0f;
    else if (tid < 2 * B) counts[tid - B] = 0.0f;

    if (wave >= B) return;

    const f4 a = *(reinterpret_cast<const f4*>(anchor + (size_t)wave * 256) + lane);
    const f4 p = *(reinterpret_cast<const f4*>(pos    + (size_t)wave * 256) + lane);

    float dot = dot4(a, p);
    float na  = dot4(a, a);
    float nb  = dot4(p, p);

    #pragma unroll
    for (int off = 32; off > 0; off >>= 1) {
        dot += __shfl_xor(dot, off);
        na  += __shfl_xor(na,  off);
        nb  += __shfl_xor(nb,  off);
    }
    if (lane == 0) {
        float sna = sqrtf(na);
        float2 r;
        r.x = dot / fmaxf(sna * sqrtf(nb), EPS);  // pos_sim
        r.y = sna;                                 // ||anchor||
        pn[wave] = r;
    }
}

// ---------------- Kernel 2: negatives, 16-lane groups ----------------------
// Each 1/4-wave (16 lanes) owns one negative: lane accumulates 4 f4 chunks
// locally (VALU only), then a 4-step 16-lane butterfly -> 2 shuffle insts
// per negative (was 12). Wave processes 32 CONTIGUOUS negatives (32 KB
// sequential stream); 8 negs (16 KB) in flight per iteration.
__global__ void __launch_bounds__(256) neg_kernel(
        const float* __restrict__ anchor,
        const float* __restrict__ neg,
        const int*  __restrict__ idx,
        const float2* __restrict__ pn,
        float* __restrict__ sums,
        float* __restrict__ counts,
        int N) {
    const int lane  = threadIdx.x & 63;
    const int wid   = threadIdx.x >> 6;
    const int group = lane >> 4;      // 0..3: which negative in the quad
    const int glane = lane & 15;      // position within group
    const int gwave = blockIdx.x * (blockDim.x >> 6) + wid;
    const long long base = (long long)gwave * NEG_PER_WAVE;
    if (base >= N) return;

    const bool full = (base + NEG_PER_WAVE) <= N;

    #pragma unroll 1
    for (int it = 0; it < NEG_PER_WAVE; it += 8) {
        const long long nA = base + it + group;
        const long long nB = base + it + 4 + group;
        if (!full && nB >= N) {
            // guarded tail (never taken for N % 128 == 0)
            if (nA < N) {
                const int bA = idx[nA];
                const f4* ar = reinterpret_cast<const f4*>(anchor + (size_t)bA * 256);
                const f4* nr = reinterpret_cast<const f4*>(neg + (size_t)nA * 256);
                float d = 0.0f, q = 0.0f;
                #pragma unroll
                for (int c = 0; c < 4; ++c) {
                    const f4 a = ar[c * 16 + glane];
                    const f4 v = __builtin_nontemporal_load(nr + c * 16 + glane);
                    d += dot4(a, v); q += dot4(v, v);
                }
                #pragma unroll
                for (int off = 8; off > 0; off >>= 1) {
                    d += __shfl_xor(d, off);
                    q += __shfl_xor(q, off);
                }
                if (glane == 0) {
                    const float2 p = pn[bA];
                    float t = fmaxf(MARGIN + d / fmaxf(p.y * sqrtf(q), EPS) - p.x, 0.0f);
                    atomicAdd(&sums[bA], t);
                    atomicAdd(&counts[bA], 1.0f);
                }
            }
            continue;
        }

        const int bA = idx[nA];       // 16 lanes/group share address: broadcast
        const int bB = idx[nB];

        const f4* arA = reinterpret_cast<const f4*>(anchor + (size_t)bA * 256);
        const f4* arB = reinterpret_cast<const f4*>(anchor + (size_t)bB * 256);
        const f4* nrA = reinterpret_cast<const f4*>(neg + (size_t)nA * 256);
        const f4* nrB = reinterpret_cast<const f4*>(neg + (size_t)nB * 256);

        // issue all 16 loads (16 KB/wave in flight)
        const f4 a0 = arA[ 0 + glane], a1 = arA[16 + glane],
                 a2 = arA[32 + glane], a3 = arA[48 + glane];
        const f4 c0 = arB[ 0 + glane], c1 = arB[16 + glane],
                 c2 = arB[32 + glane], c3 = arB[48 + glane];
        const f4 v0 = __builtin_nontemporal_load(nrA +  0 + glane),
                 v1 = __builtin_nontemporal_load(nrA + 16 + glane),
                 v2 = __builtin_nontemporal_load(nrA + 32 + glane),
                 v3 = __builtin_nontemporal_load(nrA + 48 + glane);
        const f4 w0 = __builtin_nontemporal_load(nrB +  0 + glane),
                 w1 = __builtin_nontemporal_load(nrB + 16 + glane),
                 w2 = __builtin_nontemporal_load(nrB + 32 + glane),
                 w3 = __builtin_nontemporal_load(nrB + 48 + glane);

        float dA = dot4(a0, v0) + dot4(a1, v1) + dot4(a2, v2) + dot4(a3, v3);
        float qA = dot4(v0, v0) + dot4(v1, v1) + dot4(v2, v2) + dot4(v3, v3);
        float dB = dot4(c0, w0) + dot4(c1, w1) + dot4(c2, w2) + dot4(c3, w3);
        float qB = dot4(w0, w0) + dot4(w1, w1) + dot4(w2, w2) + dot4(w3, w3);

        // 16-lane butterfly: 4 steps x 4 quantities = 16 shuffle insts / 8 negs
        #pragma unroll
        for (int off = 8; off > 0; off >>= 1) {
            dA += __shfl_xor(dA, off);  qA += __shfl_xor(qA, off);
            dB += __shfl_xor(dB, off);  qB += __shfl_xor(qB, off);
        }

        if (glane == 0) {
            const float2 pA = pn[bA];
            const float2 pB = pn[bB];
            float tA = fmaxf(MARGIN + dA / fmaxf(pA.y * sqrtf(qA), EPS) - pA.x, 0.0f);
            float tB = fmaxf(MARGIN + dB / fmaxf(pB.y * sqrtf(qB), EPS) - pB.x, 0.0f);
            atomicAdd(&sums[bA], tA);  atomicAdd(&counts[bA], 1.0f);
            atomicAdd(&sums[bB], tB);  atomicAdd(&counts[bB], 1.0f);
        }
    }
}

// ---------------- Kernel 3: segment means -> scalar (one block) ------------
__global__ void __launch_bounds__(1024) finalize_kernel(
        const float* __restrict__ sums,
        const float* __restrict__ counts,
        float* __restrict__ out, int B) {
    float local = 0.0f;
    for (int i = threadIdx.x; i < B; i += blockDim.x) {
        float c = counts[i];
        local += (c > 0.0f) ? (sums[i] / c) : 0.0f;
    }
    #pragma unroll
    for (int off = 32; off > 0; off >>= 1)
        local += __shfl_xor(local, off);

    __shared__ float ws[16];
    const int wid = threadIdx.x >> 6;
    if ((threadIdx.x & 63) == 0) ws[wid] = local;
    __syncthreads();
    if (threadIdx.x == 0) {
        float tot = 0.0f;
        const int nw = blockDim.x >> 6;
        for (int w = 0; w < nw; ++w) tot += ws[w];
        out[0] = tot / (float)B;
    }
}

extern "C" void kernel_launch(void* const* d_in, const int* in_sizes, int n_in,
                              void* d_out, int out_size, void* d_ws, size_t ws_size,
                              hipStream_t stream) {
    const float* anchor = (const float*)d_in[0];
    const float* pos    = (const float*)d_in[1];
    const float* neg    = (const float*)d_in[2];
    const int*   idx    = (const int*)d_in[3];

    const int D = 256;
    int B = in_sizes[0] / D;   // 4096
    int N = in_sizes[3];       // 262144

    float2* pn     = (float2*)d_ws;            // B float2
    float*  sums   = (float*)(pn + B);         // B floats
    float*  counts = sums + B;                 // B floats

    // kernel 1: B waves; also zeroes sums/counts (stream-ordered before k2)
    {
        int threads = 256;
        int blocks = (B + 3) / 4;   // 1024 blocks, 64*B threads total
        pos_sim_kernel<<<blocks, threads, 0, stream>>>(anchor, pos, pn,
                                                       sums, counts, B);
    }

    // kernel 2: contiguous 32 negs per wave; 128 per block
    {
        int threads = 256;
        int negs_per_block = (threads / 64) * NEG_PER_WAVE;  // 128
        int blocks = (N + negs_per_block - 1) / negs_per_block;  // 2048
        neg_kernel<<<blocks, threads, 0, stream>>>(anchor, neg, idx, pn,
                                                   sums, counts, N);
    }

    // kernel 3: one block, direct write (no memset, no atomic)
    finalize_kernel<<<1, 1024, 0, stream>>>(sums, counts, (float*)d_out, B);
}

// Round 6
// 68.941 us; speedup vs baseline: 1.4350x; 1.1286x over previous
//
#include <hip/hip_runtime.h>
#include <math.h>

#define EPS 1e-8f
#define MARGIN 0.5f
#define NEG_PER_WAVE 32

typedef float   f4 __attribute__((ext_vector_type(4)));
typedef _Float16 h4 __attribute__((ext_vector_type(4)));

__device__ __forceinline__ float dot4(const f4 a, const f4 b) {
    return a.x * b.x + a.y * b.y + a.z * b.z + a.w * b.w;
}
__device__ __forceinline__ float dot4h(const h4 a, const f4 b) {
    return (float)a.x * b.x + (float)a.y * b.y + (float)a.z * b.z + (float)a.w * b.w;
}

// ============================ FP16-anchor path ==============================

// Kernel 1h: pos cosine + write normalized fp16 anchor table + zero accums.
__global__ void pos_h_kernel(const float* __restrict__ anchor,
                             const float* __restrict__ pos,
                             _Float16* __restrict__ a_h,
                             float* __restrict__ ps,
                             float* __restrict__ sums,
                             float* __restrict__ counts,
                             int B) {
    const int tid  = blockIdx.x * blockDim.x + threadIdx.x;
    const int row  = tid >> 6;
    const int lane = threadIdx.x & 63;

    if (tid < B) sums[tid] = 0.0f;
    else if (tid < 2 * B) counts[tid - B] = 0.0f;

    if (row >= B) return;

    const f4 a = *(reinterpret_cast<const f4*>(anchor + (size_t)row * 256) + lane);
    const f4 p = *(reinterpret_cast<const f4*>(pos    + (size_t)row * 256) + lane);

    float dot = dot4(a, p);
    float na  = dot4(a, a);
    float nb  = dot4(p, p);

    #pragma unroll
    for (int off = 32; off > 0; off >>= 1) {
        dot += __shfl_xor(dot, off);
        na  += __shfl_xor(na,  off);
        nb  += __shfl_xor(nb,  off);
    }
    const float sna   = sqrtf(na);                 // every lane has full sum
    const float scale = 1.0f / fmaxf(sna, 1e-20f);

    h4 ah;
    ah.x = (_Float16)(a.x * scale);
    ah.y = (_Float16)(a.y * scale);
    ah.z = (_Float16)(a.z * scale);
    ah.w = (_Float16)(a.w * scale);
    *(reinterpret_cast<h4*>(a_h + (size_t)row * 256) + lane) = ah;

    if (lane == 0)
        ps[row] = dot / fmaxf(sna * sqrtf(nb), EPS);
}

// Kernel 2h: negatives vs fp16-normalized anchors. 16-lane group per
// negative, 4 negs per step, unroll-2 so next step's loads overlap the
// butterfly+atomics of the current step.
__global__ void __launch_bounds__(256) neg_h_kernel(
        const _Float16* __restrict__ a_h,
        const float* __restrict__ neg,
        const int*  __restrict__ idx,
        const float* __restrict__ ps,
        float* __restrict__ sums,
        float* __restrict__ counts,
        int N) {
    const int lane  = threadIdx.x & 63;
    const int wid   = threadIdx.x >> 6;
    const int group = lane >> 4;
    const int glane = lane & 15;
    const long long base =
        ((long long)blockIdx.x * (blockDim.x >> 6) + wid) * NEG_PER_WAVE;
    if (base >= N) return;

    if (base + NEG_PER_WAVE <= N) {
        #pragma unroll 2
        for (int it = 0; it < NEG_PER_WAVE; it += 4) {
            const long long n = base + it + group;
            const int b = idx[n];

            const f4* nr = reinterpret_cast<const f4*>(neg + (size_t)n * 256);
            const h4* ar = reinterpret_cast<const h4*>(a_h + (size_t)b * 256);

            // element sets match: chunk c covers elems c*64 + glane*4 .. +3
            const f4 v0 = __builtin_nontemporal_load(nr +  0 + glane);
            const f4 v1 = __builtin_nontemporal_load(nr + 16 + glane);
            const f4 v2 = __builtin_nontemporal_load(nr + 32 + glane);
            const f4 v3 = __builtin_nontemporal_load(nr + 48 + glane);
            const h4 a0 = ar[ 0 + glane], a1 = ar[16 + glane],
                     a2 = ar[32 + glane], a3 = ar[48 + glane];

            float d = dot4h(a0, v0) + dot4h(a1, v1) + dot4h(a2, v2) + dot4h(a3, v3);
            float q = dot4(v0, v0) + dot4(v1, v1) + dot4(v2, v2) + dot4(v3, v3);

            #pragma unroll
            for (int off = 8; off > 0; off >>= 1) {
                d += __shfl_xor(d, off);
                q += __shfl_xor(q, off);
            }
            if (glane == 0) {
                float t = fmaxf(MARGIN + d / sqrtf(fmaxf(q, 1e-30f)) - ps[b], 0.0f);
                atomicAdd(&sums[b], t);
                atomicAdd(&counts[b], 1.0f);
            }
        }
    } else {
        for (int it = 0; it < NEG_PER_WAVE; it += 4) {
            const long long n = base + it + group;
            if (n >= N) continue;
            const int b = idx[n];
            const f4* nr = reinterpret_cast<const f4*>(neg + (size_t)n * 256);
            const h4* ar = reinterpret_cast<const h4*>(a_h + (size_t)b * 256);
            const f4 v0 = __builtin_nontemporal_load(nr +  0 + glane);
            const f4 v1 = __builtin_nontemporal_load(nr + 16 + glane);
            const f4 v2 = __builtin_nontemporal_load(nr + 32 + glane);
            const f4 v3 = __builtin_nontemporal_load(nr + 48 + glane);
            const h4 a0 = ar[ 0 + glane], a1 = ar[16 + glane],
                     a2 = ar[32 + glane], a3 = ar[48 + glane];
            float d = dot4h(a0, v0) + dot4h(a1, v1) + dot4h(a2, v2) + dot4h(a3, v3);
            float q = dot4(v0, v0) + dot4(v1, v1) + dot4(v2, v2) + dot4(v3, v3);
            #pragma unroll
            for (int off = 8; off > 0; off >>= 1) {
                d += __shfl_xor(d, off);
                q += __shfl_xor(q, off);
            }
            if (glane == 0) {
                float t = fmaxf(MARGIN + d / sqrtf(fmaxf(q, 1e-30f)) - ps[b], 0.0f);
                atomicAdd(&sums[b], t);
                atomicAdd(&counts[b], 1.0f);
            }
        }
    }
}

// ===================== Fallback (R5, known-good, fp32) ======================

__global__ void pos_sim_kernel(const float* __restrict__ anchor,
                               const float* __restrict__ pos,
                               float2* __restrict__ pn,
                               float* __restrict__ sums,
                               float* __restrict__ counts,
                               int B) {
    const int tid  = blockIdx.x * blockDim.x + threadIdx.x;
    const int wave = tid >> 6;
    const int lane = threadIdx.x & 63;
    if (tid < B) sums[tid] = 0.0f;
    else if (tid < 2 * B) counts[tid - B] = 0.0f;
    if (wave >= B) return;
    const f4 a = *(reinterpret_cast<const f4*>(anchor + (size_t)wave * 256) + lane);
    const f4 p = *(reinterpret_cast<const f4*>(pos    + (size_t)wave * 256) + lane);
    float dot = dot4(a, p), na = dot4(a, a), nb = dot4(p, p);
    #pragma unroll
    for (int off = 32; off > 0; off >>= 1) {
        dot += __shfl_xor(dot, off);
        na  += __shfl_xor(na,  off);
        nb  += __shfl_xor(nb,  off);
    }
    if (lane == 0) {
        float sna = sqrtf(na);
        float2 r; r.x = dot / fmaxf(sna * sqrtf(nb), EPS); r.y = sna;
        pn[wave] = r;
    }
}

__global__ void __launch_bounds__(256) neg_kernel(
        const float* __restrict__ anchor,
        const float* __restrict__ neg,
        const int*  __restrict__ idx,
        const float2* __restrict__ pn,
        float* __restrict__ sums,
        float* __restrict__ counts,
        int N) {
    const int lane  = threadIdx.x & 63;
    const int wid   = threadIdx.x >> 6;
    const int group = lane >> 4;
    const int glane = lane & 15;
    const long long base =
        ((long long)blockIdx.x * (blockDim.x >> 6) + wid) * NEG_PER_WAVE;
    if (base >= N) return;
    for (int it = 0; it < NEG_PER_WAVE; it += 4) {
        const long long n = base + it + group;
        if (n >= N) continue;
        const int b = idx[n];
        const f4* ar = reinterpret_cast<const f4*>(anchor + (size_t)b * 256);
        const f4* nr = reinterpret_cast<const f4*>(neg + (size_t)n * 256);
        float d = 0.0f, q = 0.0f;
        #pragma unroll
        for (int c = 0; c < 4; ++c) {
            const f4 a = ar[c * 16 + glane];
            const f4 v = __builtin_nontemporal_load(nr + c * 16 + glane);
            d += dot4(a, v); q += dot4(v, v);
        }
        #pragma unroll
        for (int off = 8; off > 0; off >>= 1) {
            d += __shfl_xor(d, off);
            q += __shfl_xor(q, off);
        }
        if (glane == 0) {
            const float2 p = pn[b];
            float t = fmaxf(MARGIN + d / fmaxf(p.y * sqrtf(q), EPS) - p.x, 0.0f);
            atomicAdd(&sums[b], t);
            atomicAdd(&counts[b], 1.0f);
        }
    }
}

// ---------------- Kernel 3: segment means -> scalar (one block) ------------
__global__ void __launch_bounds__(1024) finalize_kernel(
        const float* __restrict__ sums,
        const float* __restrict__ counts,
        float* __restrict__ out, int B) {
    float local = 0.0f;
    for (int i = threadIdx.x; i < B; i += blockDim.x) {
        float c = counts[i];
        local += (c > 0.0f) ? (sums[i] / c) : 0.0f;
    }
    #pragma unroll
    for (int off = 32; off > 0; off >>= 1)
        local += __shfl_xor(local, off);

    __shared__ float ws[16];
    const int wid = threadIdx.x >> 6;
    if ((threadIdx.x & 63) == 0) ws[wid] = local;
    __syncthreads();
    if (threadIdx.x == 0) {
        float tot = 0.0f;
        const int nw = blockDim.x >> 6;
        for (int w = 0; w < nw; ++w) tot += ws[w];
        out[0] = tot / (float)B;
    }
}

extern "C" void kernel_launch(void* const* d_in, const int* in_sizes, int n_in,
                              void* d_out, int out_size, void* d_ws, size_t ws_size,
                              hipStream_t stream) {
    const float* anchor = (const float*)d_in[0];
    const float* pos    = (const float*)d_in[1];
    const float* neg    = (const float*)d_in[2];
    const int*   idx    = (const int*)d_in[3];

    const int D = 256;
    int B = in_sizes[0] / D;   // 4096
    int N = in_sizes[3];       // 262144

    const size_t need_h = (size_t)B * 256 * sizeof(_Float16)  // a_h (2 MB)
                        + (size_t)B * 3 * sizeof(float);      // ps + sums + counts

    const int threads = 256;
    const int negs_per_block = (threads / 64) * NEG_PER_WAVE;          // 128
    const int nblocks = (N + negs_per_block - 1) / negs_per_block;     // 2048

    if (ws_size >= need_h) {
        // ---- fp16-anchor path ----
        _Float16* a_h   = (_Float16*)d_ws;
        float*    ps    = (float*)(a_h + (size_t)B * 256);
        float*    sums  = ps + B;
        float*    counts = sums + B;

        pos_h_kernel<<<(B + 3) / 4, threads, 0, stream>>>(anchor, pos, a_h, ps,
                                                          sums, counts, B);
        neg_h_kernel<<<nblocks, threads, 0, stream>>>(a_h, neg, idx, ps,
                                                      sums, counts, N);
        finalize_kernel<<<1, 1024, 0, stream>>>(sums, counts, (float*)d_out, B);
    } else {
        // ---- fallback: known-good R5 fp32 path ----
        float2* pn     = (float2*)d_ws;
        float*  sums   = (float*)(pn + B);
        float*  counts = sums + B;

        pos_sim_kernel<<<(B + 3) / 4, threads, 0, stream>>>(anchor, pos, pn,
                                                            sums, counts, B);
        neg_kernel<<<nblocks, threads, 0, stream>>>(anchor, neg, idx, pn,
                                                    sums, counts, N);
        finalize_kernel<<<1, 1024, 0, stream>>>(sums, counts, (float*)d_out, B);
    }
}

// Round 7
// 63.415 us; speedup vs baseline: 1.5601x; 1.0871x over previous
//
#include <hip/hip_runtime.h>
#include <math.h>

#define EPS 1e-8f
#define MARGIN 0.5f
#define NEG_PER_WAVE 32
#define FIXSCALE 1048576.0f            // 2^20 fixed-point for t
#define MASK40 ((1ULL << 40) - 1)

typedef float    f4 __attribute__((ext_vector_type(4)));
typedef _Float16 h4 __attribute__((ext_vector_type(4)));

__device__ __forceinline__ float dot4(const f4 a, const f4 b) {
    return a.x * b.x + a.y * b.y + a.z * b.z + a.w * b.w;
}
__device__ __forceinline__ float dot4h(const h4 a, const f4 b) {
    return (float)a.x * b.x + (float)a.y * b.y + (float)a.z * b.z + (float)a.w * b.w;
}

// ============================ FP16-anchor path ==============================

// Kernel 1h: pos cosine + normalized fp16 anchor table + zero u64 accums.
__global__ void pos_h_kernel(const float* __restrict__ anchor,
                             const float* __restrict__ pos,
                             _Float16* __restrict__ a_h,
                             float* __restrict__ ps,
                             unsigned long long* __restrict__ acc,
                             int B) {
    const int tid  = blockIdx.x * blockDim.x + threadIdx.x;
    const int row  = tid >> 6;
    const int lane = threadIdx.x & 63;

    // zero packed accumulators (2*B u32 words; total threads = 64*B >= 2*B)
    if (tid < 2 * B) ((unsigned int*)acc)[tid] = 0u;

    if (row >= B) return;

    const f4 a = *(reinterpret_cast<const f4*>(anchor + (size_t)row * 256) + lane);
    const f4 p = *(reinterpret_cast<const f4*>(pos    + (size_t)row * 256) + lane);

    float dot = dot4(a, p);
    float na  = dot4(a, a);
    float nb  = dot4(p, p);

    #pragma unroll
    for (int off = 32; off > 0; off >>= 1) {
        dot += __shfl_xor(dot, off);
        na  += __shfl_xor(na,  off);
        nb  += __shfl_xor(nb,  off);
    }
    const float sna   = sqrtf(na);
    const float scale = 1.0f / fmaxf(sna, 1e-20f);

    h4 ah;
    ah.x = (_Float16)(a.x * scale);
    ah.y = (_Float16)(a.y * scale);
    ah.z = (_Float16)(a.z * scale);
    ah.w = (_Float16)(a.w * scale);
    *(reinterpret_cast<h4*>(a_h + (size_t)row * 256) + lane) = ah;

    if (lane == 0)
        ps[row] = dot / fmaxf(sna * sqrtf(nb), EPS);
}

// Kernel 2h: pure-stream hot loop (loads + FMA + shfl only); results staged
// in LDS; ONE packed u64 atomic per negative, batched at wave end so no
// atomic ever sits in the vmcnt queue between load steps.
__global__ void __launch_bounds__(256) neg_h_kernel(
        const _Float16* __restrict__ a_h,
        const float* __restrict__ neg,
        const int*  __restrict__ idx,
        const float* __restrict__ ps,
        unsigned long long* __restrict__ acc,
        int N) {
    __shared__ int   sb[4][NEG_PER_WAVE];
    __shared__ float ssim[4][NEG_PER_WAVE];

    const int lane  = threadIdx.x & 63;
    const int wid   = threadIdx.x >> 6;
    const int group = lane >> 4;
    const int glane = lane & 15;
    const long long base =
        ((long long)blockIdx.x * (blockDim.x >> 6) + wid) * NEG_PER_WAVE;

    if (lane < NEG_PER_WAVE) sb[wid][lane] = -1;

    if (base < N) {
        #pragma unroll 2
        for (int it = 0; it < NEG_PER_WAVE; it += 4) {
            const long long n = base + it + group;
            const bool valid = (n < N);
            const long long ns = valid ? n : (long long)0;
            const int b = valid ? idx[ns] : 0;

            const f4* nr = reinterpret_cast<const f4*>(neg + (size_t)ns * 256);
            const h4* ar = reinterpret_cast<const h4*>(a_h + (size_t)b * 256);

            const f4 v0 = __builtin_nontemporal_load(nr +  0 + glane);
            const f4 v1 = __builtin_nontemporal_load(nr + 16 + glane);
            const f4 v2 = __builtin_nontemporal_load(nr + 32 + glane);
            const f4 v3 = __builtin_nontemporal_load(nr + 48 + glane);
            const h4 a0 = ar[ 0 + glane], a1 = ar[16 + glane],
                     a2 = ar[32 + glane], a3 = ar[48 + glane];

            float d = dot4h(a0, v0) + dot4h(a1, v1) + dot4h(a2, v2) + dot4h(a3, v3);
            float q = dot4(v0, v0) + dot4(v1, v1) + dot4(v2, v2) + dot4(v3, v3);

            #pragma unroll
            for (int off = 8; off > 0; off >>= 1) {
                d += __shfl_xor(d, off);
                q += __shfl_xor(q, off);
            }
            if (glane == 0 && valid) {
                sb[wid][it + group]   = b;
                ssim[wid][it + group] = d * rsqrtf(fmaxf(q, 1e-30f));
            }
        }
    }

    __syncthreads();

    // flush: lanes 0..31 each own one staged negative; one u64 atomic each,
    // all issued by a single instruction, nothing depends on them.
    if (lane < NEG_PER_WAVE) {
        const int b = sb[wid][lane];
        if (b >= 0) {
            const float sim = ssim[wid][lane];
            const float t = fmaxf(MARGIN + sim - ps[b], 0.0f);
            const unsigned long long pk =
                (unsigned long long)(t * FIXSCALE + 0.5f) + (1ULL << 40);
            atomicAdd(&acc[b], pk);
        }
    }
}

// Kernel 3h: unpack u64 accums -> segment means -> scalar (one block).
__global__ void __launch_bounds__(1024) finalize_packed_kernel(
        const unsigned long long* __restrict__ acc,
        float* __restrict__ out, int B) {
    float local = 0.0f;
    for (int i = threadIdx.x; i < B; i += blockDim.x) {
        const unsigned long long v = acc[i];
        const float c = (float)(v >> 40);
        const float s = (float)(v & MASK40) * (1.0f / FIXSCALE);
        local += (c > 0.0f) ? (s / c) : 0.0f;
    }
    #pragma unroll
    for (int off = 32; off > 0; off >>= 1)
        local += __shfl_xor(local, off);

    __shared__ float ws[16];
    const int wid = threadIdx.x >> 6;
    if ((threadIdx.x & 63) == 0) ws[wid] = local;
    __syncthreads();
    if (threadIdx.x == 0) {
        float tot = 0.0f;
        const int nw = blockDim.x >> 6;
        for (int w = 0; w < nw; ++w) tot += ws[w];
        out[0] = tot / (float)B;
    }
}

// ===================== Fallback (R5/R6, known-good, fp32) ===================

__global__ void pos_sim_kernel(const float* __restrict__ anchor,
                               const float* __restrict__ pos,
                               float2* __restrict__ pn,
                               float* __restrict__ sums,
                               float* __restrict__ counts,
                               int B) {
    const int tid  = blockIdx.x * blockDim.x + threadIdx.x;
    const int wave = tid >> 6;
    const int lane = threadIdx.x & 63;
    if (tid < B) sums[tid] = 0.0f;
    else if (tid < 2 * B) counts[tid - B] = 0.0f;
    if (wave >= B) return;
    const f4 a = *(reinterpret_cast<const f4*>(anchor + (size_t)wave * 256) + lane);
    const f4 p = *(reinterpret_cast<const f4*>(pos    + (size_t)wave * 256) + lane);
    float dot = dot4(a, p), na = dot4(a, a), nb = dot4(p, p);
    #pragma unroll
    for (int off = 32; off > 0; off >>= 1) {
        dot += __shfl_xor(dot, off);
        na  += __shfl_xor(na,  off);
        nb  += __shfl_xor(nb,  off);
    }
    if (lane == 0) {
        float sna = sqrtf(na);
        float2 r; r.x = dot / fmaxf(sna * sqrtf(nb), EPS); r.y = sna;
        pn[wave] = r;
    }
}

__global__ void __launch_bounds__(256) neg_kernel(
        const float* __restrict__ anchor,
        const float* __restrict__ neg,
        const int*  __restrict__ idx,
        const float2* __restrict__ pn,
        float* __restrict__ sums,
        float* __restrict__ counts,
        int N) {
    const int lane  = threadIdx.x & 63;
    const int wid   = threadIdx.x >> 6;
    const int group = lane >> 4;
    const int glane = lane & 15;
    const long long base =
        ((long long)blockIdx.x * (blockDim.x >> 6) + wid) * NEG_PER_WAVE;
    if (base >= N) return;
    for (int it = 0; it < NEG_PER_WAVE; it += 4) {
        const long long n = base + it + group;
        if (n >= N) continue;
        const int b = idx[n];
        const f4* ar = reinterpret_cast<const f4*>(anchor + (size_t)b * 256);
        const f4* nr = reinterpret_cast<const f4*>(neg + (size_t)n * 256);
        float d = 0.0f, q = 0.0f;
        #pragma unroll
        for (int c = 0; c < 4; ++c) {
            const f4 a = ar[c * 16 + glane];
            const f4 v = __builtin_nontemporal_load(nr + c * 16 + glane);
            d += dot4(a, v); q += dot4(v, v);
        }
        #pragma unroll
        for (int off = 8; off > 0; off >>= 1) {
            d += __shfl_xor(d, off);
            q += __shfl_xor(q, off);
        }
        if (glane == 0) {
            const float2 p = pn[b];
            float t = fmaxf(MARGIN + d / fmaxf(p.y * sqrtf(q), EPS) - p.x, 0.0f);
            atomicAdd(&sums[b], t);
            atomicAdd(&counts[b], 1.0f);
        }
    }
}

__global__ void __launch_bounds__(1024) finalize_kernel(
        const float* __restrict__ sums,
        const float* __restrict__ counts,
        float* __restrict__ out, int B) {
    float local = 0.0f;
    for (int i = threadIdx.x; i < B; i += blockDim.x) {
        float c = counts[i];
        local += (c > 0.0f) ? (sums[i] / c) : 0.0f;
    }
    #pragma unroll
    for (int off = 32; off > 0; off >>= 1)
        local += __shfl_xor(local, off);

    __shared__ float ws[16];
    const int wid = threadIdx.x >> 6;
    if ((threadIdx.x & 63) == 0) ws[wid] = local;
    __syncthreads();
    if (threadIdx.x == 0) {
        float tot = 0.0f;
        const int nw = blockDim.x >> 6;
        for (int w = 0; w < nw; ++w) tot += ws[w];
        out[0] = tot / (float)B;
    }
}

extern "C" void kernel_launch(void* const* d_in, const int* in_sizes, int n_in,
                              void* d_out, int out_size, void* d_ws, size_t ws_size,
                              hipStream_t stream) {
    const float* anchor = (const float*)d_in[0];
    const float* pos    = (const float*)d_in[1];
    const float* neg    = (const float*)d_in[2];
    const int*   idx    = (const int*)d_in[3];

    const int D = 256;
    int B = in_sizes[0] / D;   // 4096
    int N = in_sizes[3];       // 262144

    const size_t need_h = (size_t)B * 256 * sizeof(_Float16)            // a_h
                        + (size_t)B * sizeof(float)                     // ps
                        + (size_t)B * sizeof(unsigned long long);       // acc

    const int threads = 256;
    const int negs_per_block = (threads / 64) * NEG_PER_WAVE;           // 128
    const int nblocks = (N + negs_per_block - 1) / negs_per_block;      // 2048

    if (ws_size >= need_h) {
        _Float16*           a_h = (_Float16*)d_ws;
        float*              ps  = (float*)(a_h + (size_t)B * 256);
        unsigned long long* acc = (unsigned long long*)(ps + B);

        pos_h_kernel<<<(B + 3) / 4, threads, 0, stream>>>(anchor, pos, a_h, ps,
                                                          acc, B);
        neg_h_kernel<<<nblocks, threads, 0, stream>>>(a_h, neg, idx, ps,
                                                      acc, N);
        finalize_packed_kernel<<<1, 1024, 0, stream>>>(acc, (float*)d_out, B);
    } else {
        // fallback: known-good fp32 path
        float2* pn     = (float2*)d_ws;
        float*  sums   = (float*)(pn + B);
        float*  counts = sums + B;

        pos_sim_kernel<<<(B + 3) / 4, threads, 0, stream>>>(anchor, pos, pn,
                                                            sums, counts, B);
        neg_kernel<<<nblocks, threads, 0, stream>>>(anchor, neg, idx, pn,
                                                    sums, counts, N);
        finalize_kernel<<<1, 1024, 0, stream>>>(sums, counts, (float*)d_out, B);
    }
}